// Round 15
// baseline (22.514 us; speedup 1.0000x reference)
//
#include <hip/hip_runtime.h>

#define GAMMA 0.99f
#define TAU   0.95f
#define GTAU  (GAMMA * TAU)

constexpr int TSEQ   = 4;             // elements per lane per tile (one float4)
constexpr int TILE   = 64 * TSEQ;     // 256 elements per tile
constexpr int WCHUNK = 2 * TILE;      // 512 elements per wave (two tiles)
constexpr int BLK    = 256;           // 4 independent waves per block

typedef float fx4 __attribute__((ext_vector_type(4)));

// (A,B) = (A,B) ∘ (rA,rB)  — apply right operand first, then (A,B)
__device__ __forceinline__ void post_compose(float& A, float& B, float rA, float rB) {
    B = fmaf(A, rB, B);
    A *= rA;
}
// (A,B) = (lA,lB) ∘ (A,B)  — apply (A,B) first, then left operand
__device__ __forceinline__ void pre_compose(float& A, float& B, float lA, float lB) {
    B = fmaf(lA, B, lB);
    A *= lA;
}

// suffix scan over the wave (inclusive in place) + thread-exclusive output
__device__ __forceinline__ void scan_excl(
    int lane, float& Aa, float& Ba, float& Ar, float& Br,
    float& eAa, float& eBa, float& eAr, float& eBr)
{
    #pragma unroll
    for (int st = 1; st < 64; st <<= 1) {
        float oAa = __shfl_down(Aa, st);
        float oBa = __shfl_down(Ba, st);
        float oAr = __shfl_down(Ar, st);
        float oBr = __shfl_down(Br, st);
        if (lane + st < 64) {
            post_compose(Aa, Ba, oAa, oBa);
            post_compose(Ar, Br, oAr, oBr);
        }
    }
    eAa = __shfl_down(Aa, 1);
    eBa = __shfl_down(Ba, 1);
    eAr = __shfl_down(Ar, 1);
    eBr = __shfl_down(Br, 1);
    if (lane == 63) { eAa = 1.f; eBa = 0.f; eAr = 1.f; eBr = 0.f; }
}

// =====================================================================
// Wave-independent GAE scan, two 256-element tiles per wave.
//  - each tile keeps the verified perfectly-coalesced layout (lane i's
//    float4 at tileBase + i*16B).
//  - only the RIGHT tile pays the carry-window search; the left tile's
//    carry is the right tile's lane-0 leftmost replay value (one shfl).
//    -> window overhead halves vs one-tile waves (round 14's 22.4us).
//  - carry: at m[i]==0 both recurrences reset (map A=0 annihilates all
//    later terms), so composing element maps rightward from p to the
//    first m==0 / array end is the EXACT carry. Bernoulli masks -> one
//    64-wide batch suffices with prob 1-2^-64 (loop continues if not).
//  - NT stores: outputs never re-read; keep LLC for re-read inputs.
// =====================================================================
__global__ __launch_bounds__(BLK, 4) void k_wave2(
    const float* __restrict__ r, const float* __restrict__ v,
    const float* __restrict__ nv, const int* __restrict__ m,
    float* __restrict__ out_adv, float* __restrict__ out_ret, int T, int nchunk)
{
    const int  lane  = threadIdx.x & 63;
    const int  w     = threadIdx.x >> 6;
    const int  chunk = (int)blockIdx.x * 4 + w;
    if (chunk >= nchunk) return;                       // wave-uniform exit

    const long cstart = (long)chunk * WCHUNK;
    const long baseA  = cstart + (long)lane * TSEQ;           // left tile
    const long baseB  = cstart + TILE + (long)lane * TSEQ;    // right tile
    const long p      = cstart + WCHUNK;                      // next chunk start

    // ---- carry-window prefetch (all 64 lanes, issued first) ----
    float pm = 0.f, pr = 0.f, pv = 0.f, pv1 = 0.f, pnv = 0.f;
    if (p < (long)T) {
        long i = p + lane;
        if (i < (long)T) {
            pm  = (float)m[i];
            pr  = r[i];
            pv  = v[i];
            pv1 = (i + 1 < (long)T) ? v[i + 1] : 0.f;
            pnv = nv[i];
        }
    }

    const bool full = (p <= (long)T);                  // whole 512 in range

    float dA[TSEQ], ddA[TSEQ], dB[TSEQ], ddB[TSEQ];
    unsigned vbA = 0, mbA = 0, vbB = 0, mbB = 0;
    float AaA=1.f, BaA=0.f, ArA=1.f, BrA=0.f;
    float AaB=1.f, BaB=0.f, ArB=1.f, BrB=0.f;

    if (full) {
        vbA = 0xFu; vbB = 0xFu;
        float4 r4a = *(const float4*)(r  + baseA);
        float4 r4b = *(const float4*)(r  + baseB);
        float4 v4a = *(const float4*)(v  + baseA);
        float4 v4b = *(const float4*)(v  + baseB);
        float4 n4a = *(const float4*)(nv + baseA);
        float4 n4b = *(const float4*)(nv + baseB);
        int4   m4a = *(const int4*)  (m  + baseA);
        int4   m4b = *(const int4*)  (m  + baseB);

        float vp  = __shfl(pv, 0);                     // v[p] (0 if p>=T)
        float vb0 = __shfl(v4b.x, 0);                  // v at right-tile start
        float vnB = __shfl_down(v4b.x, 1);
        float vnA = __shfl_down(v4a.x, 1);
        float vnextB = (lane == 63) ? vp  : vnB;
        float vnextA = (lane == 63) ? vb0 : vnA;

        {   // right tile maps
            float rr[4]  = {r4b.x, r4b.y, r4b.z, r4b.w};
            float vv[5]  = {v4b.x, v4b.y, v4b.z, v4b.w, vnextB};
            float nn[4]  = {n4b.x, n4b.y, n4b.z, n4b.w};
            float fmv[4] = {(float)m4b.x, (float)m4b.y, (float)m4b.z, (float)m4b.w};
            #pragma unroll
            for (int i = TSEQ - 1; i >= 0; --i) {
                if (fmv[i] != 0.f) mbB |= (1u << i);
                dB[i]  = rr[i] + GAMMA * fmv[i] * vv[i+1] - vv[i];
                ddB[i] = rr[i] + GAMMA * (1.f - fmv[i]) * nn[i];
                pre_compose(AaB, BaB, GTAU  * fmv[i], dB[i]);
                pre_compose(ArB, BrB, GAMMA * fmv[i], ddB[i]);
            }
        }
        {   // left tile maps
            float rr[4]  = {r4a.x, r4a.y, r4a.z, r4a.w};
            float vv[5]  = {v4a.x, v4a.y, v4a.z, v4a.w, vnextA};
            float nn[4]  = {n4a.x, n4a.y, n4a.z, n4a.w};
            float fmv[4] = {(float)m4a.x, (float)m4a.y, (float)m4a.z, (float)m4a.w};
            #pragma unroll
            for (int i = TSEQ - 1; i >= 0; --i) {
                if (fmv[i] != 0.f) mbA |= (1u << i);
                dA[i]  = rr[i] + GAMMA * fmv[i] * vv[i+1] - vv[i];
                ddA[i] = rr[i] + GAMMA * (1.f - fmv[i]) * nn[i];
                pre_compose(AaA, BaA, GTAU  * fmv[i], dA[i]);
                pre_compose(ArA, BrA, GAMMA * fmv[i], ddA[i]);
            }
        }
    } else {
        // tail: per-element scalar, per tile
        #pragma unroll
        for (int ii = 0; ii < TSEQ; ++ii) {
            int i = TSEQ - 1 - ii;
            long idx = baseB + i;
            bool val = idx < (long)T;
            float rr  = val ? r[idx]  : 0.f;
            float vv0 = val ? v[idx]  : 0.f;
            float vv1 = (idx + 1 < (long)T) ? v[idx + 1] : 0.f;
            float nn  = val ? nv[idx] : 0.f;
            float fmv = val ? (float)m[idx] : 0.f;
            if (val) vbB |= (1u << i);
            if (val && fmv != 0.f) mbB |= (1u << i);
            dB[i]  = val ? (rr + GAMMA * fmv * vv1 - vv0) : 0.f;
            ddB[i] = val ? (rr + GAMMA * (1.f - fmv) * nn) : 0.f;
            pre_compose(AaB, BaB, val ? GTAU * fmv  : 1.f, dB[i]);
            pre_compose(ArB, BrB, val ? GAMMA * fmv : 1.f, ddB[i]);
        }
        #pragma unroll
        for (int ii = 0; ii < TSEQ; ++ii) {
            int i = TSEQ - 1 - ii;
            long idx = baseA + i;
            bool val = idx < (long)T;
            float rr  = val ? r[idx]  : 0.f;
            float vv0 = val ? v[idx]  : 0.f;
            float vv1 = (idx + 1 < (long)T) ? v[idx + 1] : 0.f;
            float nn  = val ? nv[idx] : 0.f;
            float fmv = val ? (float)m[idx] : 0.f;
            if (val) vbA |= (1u << i);
            if (val && fmv != 0.f) mbA |= (1u << i);
            dA[i]  = val ? (rr + GAMMA * fmv * vv1 - vv0) : 0.f;
            ddA[i] = val ? (rr + GAMMA * (1.f - fmv) * nn) : 0.f;
            pre_compose(AaA, BaA, val ? GTAU * fmv  : 1.f, dA[i]);
            pre_compose(ArA, BrA, val ? GAMMA * fmv : 1.f, ddA[i]);
        }
    }

    // ---- scans (both tiles) ----
    float eAaB, eBaB, eArB, eBrB, eAaA, eBaA, eArA, eBrA;
    scan_excl(lane, AaB, BaB, ArB, BrB, eAaB, eBaB, eArB, eBrB);
    scan_excl(lane, AaA, BaA, ArA, BrA, eAaA, eBaA, eArA, eBrA);

    // ---- carry at p: compose element maps to first m==0 (all lanes) ----
    float cbA = 0.f, cbR = 0.f;
    if (p < (long)T) {
        float MAa, MBa, MAr, MBr;
        {
            long i = p + lane;
            bool have = i < (long)T;
            float aA=1.f, aB=0.f, rA_=1.f, rB_=0.f;
            if (have) {
                aA  = GTAU * pm;
                aB  = pr + GAMMA * pm * pv1 - pv;
                rA_ = GAMMA * pm;
                rB_ = pr + GAMMA * (1.f - pm) * pnv;
            }
            bool term = (!have) || (pm == 0.f);
            unsigned long long bz = __ballot(term);
            #pragma unroll
            for (int st = 1; st < 64; st <<= 1) {
                float oAa = __shfl_down(aA,  st);
                float oBa = __shfl_down(aB,  st);
                float oAr = __shfl_down(rA_, st);
                float oBr = __shfl_down(rB_, st);
                if (lane + st < 64) {
                    post_compose(aA,  aB,  oAa, oBa);
                    post_compose(rA_, rB_, oAr, oBr);
                }
            }
            MAa = __shfl(aA, 0);  MBa = __shfl(aB, 0);
            MAr = __shfl(rA_, 0); MBr = __shfl(rB_, 0);
            if (bz == 0ull) {
                for (long jb = p + 64; ; jb += 64) {
                    long i2 = jb + lane;
                    bool have2 = i2 < (long)T;
                    float aA2=1.f, aB2=0.f, rA2=1.f, rB2=0.f;
                    float mi = 0.f;
                    if (have2) {
                        mi = (float)m[i2];
                        float ri  = r[i2];
                        float vi  = v[i2];
                        float vi1 = (i2 + 1 < (long)T) ? v[i2 + 1] : 0.f;
                        float nvi = nv[i2];
                        aA2 = GTAU * mi;
                        aB2 = ri + GAMMA * mi * vi1 - vi;
                        rA2 = GAMMA * mi;
                        rB2 = ri + GAMMA * (1.f - mi) * nvi;
                    }
                    bool term2 = (!have2) || (mi == 0.f);
                    unsigned long long bz2 = __ballot(term2);
                    #pragma unroll
                    for (int st = 1; st < 64; st <<= 1) {
                        float oAa = __shfl_down(aA2, st);
                        float oBa = __shfl_down(aB2, st);
                        float oAr = __shfl_down(rA2, st);
                        float oBr = __shfl_down(rB2, st);
                        if (lane + st < 64) {
                            post_compose(aA2, aB2, oAa, oBa);
                            post_compose(rA2, rB2, oAr, oBr);
                        }
                    }
                    float bAa = __shfl(aA2, 0), bBa = __shfl(aB2, 0);
                    float bAr = __shfl(rA2, 0), bBr = __shfl(rB2, 0);
                    post_compose(MAa, MBa, bAa, bBa);
                    post_compose(MAr, MBr, bAr, bBr);
                    if (bz2 != 0ull) break;
                }
            }
        }
        cbA = MBa;   // adv[p]
        cbR = MBr;   // ret[p]
    }

    // ---- replay + store: right tile first, then chain carry to left tile ----
    float xa = fmaf(eAaB, cbA, eBaB);
    float xr = fmaf(eArB, cbR, eBrB);

    if (full) {
        float ta[4], tr[4];
        #pragma unroll
        for (int i = TSEQ - 1; i >= 0; --i) {
            float a  = (mbB >> i & 1u) ? GTAU  : 0.f;
            float cc = (mbB >> i & 1u) ? GAMMA : 0.f;
            xa = fmaf(a,  xa, dB[i]);
            xr = fmaf(cc, xr, ddB[i]);
            ta[i] = xa; tr[i] = xr;
        }
        fx4 va = {ta[0], ta[1], ta[2], ta[3]};
        fx4 vr = {tr[0], tr[1], tr[2], tr[3]};
        __builtin_nontemporal_store(va, (fx4*)(out_adv + baseB));
        __builtin_nontemporal_store(vr, (fx4*)(out_ret + baseB));
    } else {
        #pragma unroll
        for (int i = TSEQ - 1; i >= 0; --i) {
            bool val = (vbB >> i) & 1u;
            float a  = val ? ((mbB >> i & 1u) ? GTAU  : 0.f) : 1.f;
            float cc = val ? ((mbB >> i & 1u) ? GAMMA : 0.f) : 1.f;
            xa = fmaf(a,  xa, dB[i]);
            xr = fmaf(cc, xr, ddB[i]);
            if (baseB + i < (long)T) {
                out_adv[baseB + i] = xa;
                out_ret[baseB + i] = xr;
            }
        }
    }

    // left tile's carry = right tile's lane-0 leftmost value (= adv/ret at cstart+TILE)
    float cbA2 = __shfl(xa, 0);
    float cbR2 = __shfl(xr, 0);

    xa = fmaf(eAaA, cbA2, eBaA);
    xr = fmaf(eArA, cbR2, eBrA);

    if (full) {
        float ta[4], tr[4];
        #pragma unroll
        for (int i = TSEQ - 1; i >= 0; --i) {
            float a  = (mbA >> i & 1u) ? GTAU  : 0.f;
            float cc = (mbA >> i & 1u) ? GAMMA : 0.f;
            xa = fmaf(a,  xa, dA[i]);
            xr = fmaf(cc, xr, ddA[i]);
            ta[i] = xa; tr[i] = xr;
        }
        fx4 va = {ta[0], ta[1], ta[2], ta[3]};
        fx4 vr = {tr[0], tr[1], tr[2], tr[3]};
        __builtin_nontemporal_store(va, (fx4*)(out_adv + baseA));
        __builtin_nontemporal_store(vr, (fx4*)(out_ret + baseA));
    } else {
        #pragma unroll
        for (int i = TSEQ - 1; i >= 0; --i) {
            bool val = (vbA >> i) & 1u;
            float a  = val ? ((mbA >> i & 1u) ? GTAU  : 0.f) : 1.f;
            float cc = val ? ((mbA >> i & 1u) ? GAMMA : 0.f) : 1.f;
            xa = fmaf(a,  xa, dA[i]);
            xr = fmaf(cc, xr, ddA[i]);
            if (baseA + i < (long)T) {
                out_adv[baseA + i] = xa;
                out_ret[baseA + i] = xr;
            }
        }
    }
}

extern "C" void kernel_launch(void* const* d_in, const int* in_sizes, int n_in,
                              void* d_out, int out_size, void* d_ws, size_t ws_size,
                              hipStream_t stream) {
    const float* r  = (const float*)d_in[0];
    const float* v  = (const float*)d_in[1];
    const float* nv = (const float*)d_in[2];
    const int*   m  = (const int*)d_in[3];
    const int T = in_sizes[0];
    const int nchunk = (T + WCHUNK - 1) / WCHUNK;   // 8192 for T = 2^22
    const int nblk   = (nchunk + 3) / 4;

    float* out_adv = (float*)d_out;
    float* out_ret = (float*)d_out + T;

    k_wave2<<<nblk, BLK, 0, stream>>>(r, v, nv, m, out_adv, out_ret, T, nchunk);
}